// Round 16
// baseline (496.321 us; speedup 1.0000x reference)
//
#include <hip/hip_runtime.h>
#include <hip/hip_cooperative_groups.h>
#include <cstddef>

namespace cg = cooperative_groups;

#define NB    4
#define NTOK  8192
#define DIMX  256
#define NH    8
#define HD    64
#define INNER 512
#define SPLIT 32
#define EPS   1e-5f

typedef __attribute__((ext_vector_type(8))) short short8;
typedef __attribute__((ext_vector_type(4))) float f32x4;

__device__ __forceinline__ unsigned short f2bf(float f) {
  union { float f; unsigned u; } v; v.f = f;
  unsigned r = v.u + 0x7fffu + ((v.u >> 16) & 1u);   // RNE
  return (unsigned short)(r >> 16);
}

__device__ __forceinline__ short8 cvt8(float4 a, float4 b) {
  short8 p;
  p[0] = (short)f2bf(a.x); p[1] = (short)f2bf(a.y);
  p[2] = (short)f2bf(a.z); p[3] = (short)f2bf(a.w);
  p[4] = (short)f2bf(b.x); p[5] = (short)f2bf(b.y);
  p[6] = (short)f2bf(b.z); p[7] = (short)f2bf(b.w);
  return p;
}

// ---------------------------------------------------------------------------
// Fused pre-pass: blocks 0..2047 convert z fp32->bf16 (16 elems/thread);
// blocks 2048..2111 transpose Wkv [256][1024] fp32 -> wkvT [1024][256] bf16.
// ---------------------------------------------------------------------------
__global__ __launch_bounds__(256) void k_pre(
    const float* __restrict__ z, unsigned short* __restrict__ zb,
    const float* __restrict__ Wkv, unsigned short* __restrict__ wkvT)
{
  __shared__ unsigned short t[64][68];
  if (blockIdx.x < 2048) {
    const size_t i = ((size_t)blockIdx.x * 256 + threadIdx.x) * 16;
    float4 a0 = *(const float4*)(z + i);
    float4 a1 = *(const float4*)(z + i + 4);
    float4 a2 = *(const float4*)(z + i + 8);
    float4 a3 = *(const float4*)(z + i + 12);
    *(short8*)(zb + i) = cvt8(a0, a1);
    *(short8*)(zb + i + 8) = cvt8(a2, a3);
  } else {
    const int tid = threadIdx.x;
    const int bb = blockIdx.x - 2048;
    const int r0 = (bb & 3) * 64;
    const int c0 = (bb >> 2) * 64;
    const int r = tid >> 2;
    const int c4 = (tid & 3) * 16;
#pragma unroll
    for (int j = 0; j < 4; ++j) {
      float4 v = *(const float4*)(Wkv + (size_t)(r0 + r) * (2 * INNER) + c0 + c4 + j * 4);
      t[r][c4 + j * 4 + 0] = f2bf(v.x);
      t[r][c4 + j * 4 + 1] = f2bf(v.y);
      t[r][c4 + j * 4 + 2] = f2bf(v.z);
      t[r][c4 + j * 4 + 3] = f2bf(v.w);
    }
    __syncthreads();
    const int cc = tid >> 2;
    const int rr4 = (tid & 3) * 16;
    short8 o0, o1;
#pragma unroll
    for (int i = 0; i < 8; ++i) o0[i] = (short)t[rr4 + i][cc];
#pragma unroll
    for (int i = 0; i < 8; ++i) o1[i] = (short)t[rr4 + 8 + i][cc];
    unsigned short* dst = wkvT + (size_t)(c0 + cc) * DIMX + r0 + rr4;
    *(short8*)(dst) = o0;
    *(short8*)(dst + 8) = o1;
  }
}

// ---------------------------------------------------------------------------
// dots partials via MFMA, 2 heads per block. (round-14/15 proven)
// grid = NB * (NH/2) * SPLIT = 512 blocks, 256 threads.
// ---------------------------------------------------------------------------
__global__ __launch_bounds__(256, 2) void k_dots_mfma(
    const unsigned short* __restrict__ zb, const unsigned short* __restrict__ wkvT,
    float* __restrict__ partial)
{
  const int tid  = threadIdx.x;
  const int lane = tid & 63;
  const int w    = tid >> 6;       // wave 0..3
  const int hh   = w >> 1;         // head within pair
  const int side = w & 1;          // 0=k, 1=v
  const int l15  = lane & 15;
  const int lg   = lane >> 4;      // 0..3

  const int bid = blockIdx.x;
  const int s  = bid & (SPLIT - 1);
  const int hp = (bid >> 5) & 3;
  const int b  = bid >> 7;
  const int h  = hp * 2 + hh;

  __shared__ unsigned short zs[2][32][268];   // dbuf: 32 tok x 256 dims
  __shared__ unsigned short kv2[2][256][36];  // dbuf: [hh*128 + side*64 + dim][tok]

  // A-fragments: this wave's 64 dims (k or v of head h), all 8 K-steps.
  short8 awf[4][8];
#pragma unroll
  for (int mf = 0; mf < 4; ++mf) {
    const int dim = mf * 16 + l15;                       // 0..63
    const int gd = (side == 0) ? (h * HD + dim) : (INNER + h * HD + dim);
    const unsigned short* base = wkvT + (size_t)gd * DIMX + lg * 8;
#pragma unroll
    for (int kk = 0; kk < 8; ++kk)
      awf[mf][kk] = *(const short8*)(base + kk * 32);
  }

  f32x4 dacc[2][4];
#pragma unroll
  for (int mfr = 0; mfr < 2; ++mfr)
#pragma unroll
    for (int nfc = 0; nfc < 4; ++nfc) dacc[mfr][nfc] = (f32x4){0.f, 0.f, 0.f, 0.f};

  // staging: 32 rows, 8 threads/row, 32 bf16 (4 x short8) per thread
  const int zr = tid >> 3;
  const int zc = (tid & 7) * 32;
  const unsigned short* zbase = zb + ((size_t)b * NTOK + s * 256 + zr) * DIMX + zc;

  // prologue: stage tile 0 into buffer 0
  {
    short8 pre[4];
#pragma unroll
    for (int j = 0; j < 4; ++j) pre[j] = *(const short8*)(zbase + j * 8);
#pragma unroll
    for (int j = 0; j < 4; ++j) *(short8*)&zs[0][zr][zc + j * 8] = pre[j];
  }
  __syncthreads();

  int cur = 0;
  for (int tile = 0; tile < 8; ++tile) {
    // prefetch next z tile into regs
    short8 pre[4];
    if (tile < 7) {
      const unsigned short* src = zbase + (size_t)(tile + 1) * 32 * DIMX;
#pragma unroll
      for (int j = 0; j < 4; ++j) pre[j] = *(const short8*)(src + j * 8);
    }

    // ---- phase 1: this side's 64 dims x 32 tokens ----
    f32x4 acc[4][2];
#pragma unroll
    for (int mf = 0; mf < 4; ++mf)
#pragma unroll
      for (int nf = 0; nf < 2; ++nf) acc[mf][nf] = (f32x4){0.f, 0.f, 0.f, 0.f};

#pragma unroll
    for (int kk = 0; kk < 8; ++kk) {
      short8 bfr[2];
#pragma unroll
      for (int nf = 0; nf < 2; ++nf)
        bfr[nf] = *(const short8*)&zs[cur][nf * 16 + l15][kk * 32 + lg * 8];
#pragma unroll
      for (int mf = 0; mf < 4; ++mf)
#pragma unroll
        for (int nf = 0; nf < 2; ++nf)
          acc[mf][nf] = __builtin_amdgcn_mfma_f32_16x16x32_bf16(
              awf[mf][kk], bfr[nf], acc[mf][nf], 0, 0, 0);
    }

    // ---- per-token stats: wave-local ----
    float mu[2], rs[2];
#pragma unroll
    for (int nf = 0; nf < 2; ++nf) {
      float a = 0.f, q = 0.f;
#pragma unroll
      for (int mf = 0; mf < 4; ++mf)
#pragma unroll
        for (int r = 0; r < 4; ++r) {
          float v = acc[mf][nf][r];
          a += v; q += v * v;
        }
      a += __shfl_xor(a, 16); a += __shfl_xor(a, 32);
      q += __shfl_xor(q, 16); q += __shfl_xor(q, 32);
      const float m = a * (1.f / 64.f);
      mu[nf] = m;
      rs[nf] = rsqrtf(q * (1.f / 64.f) - m * m + EPS);
    }

    // ---- normalize, write kv2[cur] ----
#pragma unroll
    for (int mf = 0; mf < 4; ++mf)
#pragma unroll
      for (int nf = 0; nf < 2; ++nf)
#pragma unroll
        for (int r = 0; r < 4; ++r)
          kv2[cur][hh * 128 + side * 64 + mf * 16 + lg * 4 + r][nf * 16 + l15] =
              f2bf((acc[mf][nf][r] - mu[nf]) * rs[nf]);

    // stage next z tile into zs[cur^1]
    if (tile < 7) {
#pragma unroll
      for (int j = 0; j < 4; ++j) *(short8*)&zs[cur ^ 1][zr][zc + j * 8] = pre[j];
    }
    __syncthreads();   // kv2[cur] + zs[cur^1] ready

    // ---- phase 3: dots(head h) rows [side*32,+32) x all 64 v-cols ----
    {
      const int kvb = hh * 128;
      short8 a2[2], b2[4];
#pragma unroll
      for (int mfr = 0; mfr < 2; ++mfr)
        a2[mfr] = *(const short8*)&kv2[cur][kvb + side * 32 + mfr * 16 + l15][lg * 8];
#pragma unroll
      for (int nfc = 0; nfc < 4; ++nfc)
        b2[nfc] = *(const short8*)&kv2[cur][kvb + 64 + nfc * 16 + l15][lg * 8];
#pragma unroll
      for (int mfr = 0; mfr < 2; ++mfr)
#pragma unroll
        for (int nfc = 0; nfc < 4; ++nfc)
          dacc[mfr][nfc] = __builtin_amdgcn_mfma_f32_16x16x32_bf16(
              a2[mfr], b2[nfc], dacc[mfr][nfc], 0, 0, 0);
    }
    cur ^= 1;
  }

  float* pb = partial + ((size_t)((b * NH + h) * SPLIT + s)) * 4096;
#pragma unroll
  for (int mfr = 0; mfr < 2; ++mfr)
#pragma unroll
    for (int nfc = 0; nfc < 4; ++nfc)
#pragma unroll
      for (int r = 0; r < 4; ++r)
        pb[(side * 32 + mfr * 16 + lg * 4 + r) * 64 + nfc * 16 + l15] =
            dacc[mfr][nfc][r];
}

// ---------------------------------------------------------------------------
// Tail phase bodies (shared between cooperative k_tail and fallback kernels)
// ---------------------------------------------------------------------------
__device__ __forceinline__ void body_bdwout(
    int bid, int tid, float (*drow)[64],
    const float* __restrict__ partial, const float* __restrict__ Wout,
    unsigned short* __restrict__ tmpT)
{
  const int b = bid >> 7;
  const int r4 = (bid & 127) * 4;
  const int h = r4 >> 6;
  const int c = tid;

  {
    const int rr = c >> 6;          // 0..3
    const int j = c & 63;
    const float* p = partial + (size_t)(b * NH + h) * SPLIT * 4096
                   + ((r4 & 63) + rr) * 64 + j;
    float s = 0.f;
#pragma unroll
    for (int i = 0; i < SPLIT; ++i) s += p[(size_t)i * 4096];
    drow[rr][j] = s * (1.f / (float)NTOK);
  }
  __syncthreads();

  float a0 = 0.f, a1 = 0.f, a2 = 0.f, a3 = 0.f;
#pragma unroll 8
  for (int j = 0; j < 64; ++j) {
    const float wv = Wout[(size_t)(h * 64 + j) * DIMX + c];
    a0 += drow[0][j] * wv;
    a1 += drow[1][j] * wv;
    a2 += drow[2][j] * wv;
    a3 += drow[3][j] * wv;
  }
  unsigned short* tt = tmpT + ((size_t)b * DIMX + c) * INNER + r4;
  tt[0] = f2bf(a0); tt[1] = f2bf(a1); tt[2] = f2bf(a2); tt[3] = f2bf(a3);
}

__device__ __forceinline__ void body_weff(
    int bid, int tid,
    const float* __restrict__ Wq, const unsigned short* __restrict__ tmpT,
    unsigned short* __restrict__ weffT)
{
  const int lane = tid & 63;
  const int w    = tid >> 6;
  const int l15  = lane & 15;
  const int lg   = lane >> 4;

  const int b  = bid >> 5;
  const int rt = (bid >> 3) & 3;
  const int ct = bid & 7;
  const int r0 = rt * 64;
  const int c0 = ct * 32;

  const float* wq = Wq + (size_t)(r0 + w * 16 + l15) * INNER + lg * 8;
  const unsigned short* tb = tmpT + (size_t)b * DIMX * INNER + lg * 8;

  f32x4 acc[2];
  acc[0] = (f32x4){0.f, 0.f, 0.f, 0.f};
  acc[1] = (f32x4){0.f, 0.f, 0.f, 0.f};

#pragma unroll
  for (int kk = 0; kk < 16; ++kk) {
    float4 qa = *(const float4*)(wq + kk * 32);
    float4 qb = *(const float4*)(wq + kk * 32 + 4);
    short8 a = cvt8(qa, qb);
#pragma unroll
    for (int nf = 0; nf < 2; ++nf) {
      short8 b2 = *(const short8*)(tb + (size_t)(c0 + nf * 16 + l15) * INNER + kk * 32);
      acc[nf] = __builtin_amdgcn_mfma_f32_16x16x32_bf16(a, b2, acc[nf], 0, 0, 0);
    }
  }

#pragma unroll
  for (int nf = 0; nf < 2; ++nf) {
    const int c = c0 + nf * 16 + l15;
    const int r = r0 + w * 16 + lg * 4;
    unsigned long long pack = 0;
#pragma unroll
    for (int rr = 0; rr < 4; ++rr)
      pack |= (unsigned long long)f2bf(acc[nf][rr]) << (16 * rr);
    *(unsigned long long*)(weffT + ((size_t)b * DIMX + c) * DIMX + r) = pack;
  }
}

__device__ __forceinline__ void body_out(
    int bid, int tid, unsigned short* wsl /* [2][128*36] */,
    const float* __restrict__ x, const unsigned short* __restrict__ weffT,
    const float* __restrict__ bout, float* __restrict__ out)
{
  const int lane = tid & 63;
  const int w    = tid >> 6;
  const int l15  = lane & 15;
  const int lg   = lane >> 4;

  const int mt = bid & 127;
  const int ct = (bid >> 7) & 1;
  const int b  = bid >> 8;
  const int tok0 = mt * 64;
  const int col0 = ct * 128;

  // A-fragments: x row (tok0 + w*16 + l15), converted fp32->bf16.
  short8 afr[8];
  {
    const float* xr = x + ((size_t)b * NTOK + tok0 + w * 16 + l15) * DIMX + lg * 8;
#pragma unroll
    for (int kk = 0; kk < 8; ++kk) {
      float4 xa = *(const float4*)(xr + kk * 32);
      float4 xb = *(const float4*)(xr + kk * 32 + 4);
      afr[kk] = cvt8(xa, xb);
    }
  }

  f32x4 acc[8];
#pragma unroll
  for (int nf = 0; nf < 8; ++nf) acc[nf] = (f32x4){0.f, 0.f, 0.f, 0.f};

  const unsigned short* wb = weffT + (size_t)b * DIMX * DIMX
                           + (size_t)(col0 + (tid >> 1)) * DIMX + (tid & 1) * 16;
  const int c36 = (tid >> 1) * 36 + (tid & 1) * 16;

  *(short8*)&wsl[c36]     = *(const short8*)(wb);
  *(short8*)&wsl[c36 + 8] = *(const short8*)(wb + 8);
  __syncthreads();

  for (int kk = 0; kk < 8; ++kk) {
    short8 g0, g1;
    if (kk < 7) {
      g0 = *(const short8*)(wb + (kk + 1) * 32);
      g1 = *(const short8*)(wb + (kk + 1) * 32 + 8);
    }
    const unsigned short* wcur = wsl + (kk & 1) * (128 * 36);
#pragma unroll
    for (int nf = 0; nf < 8; ++nf) {
      short8 b2 = *(const short8*)&wcur[(nf * 16 + l15) * 36 + lg * 8];
      acc[nf] = __builtin_amdgcn_mfma_f32_16x16x32_bf16(afr[kk], b2, acc[nf], 0, 0, 0);
    }
    if (kk < 7) {
      unsigned short* wnxt = wsl + ((kk + 1) & 1) * (128 * 36);
      *(short8*)&wnxt[c36]     = g0;
      *(short8*)&wnxt[c36 + 8] = g1;
    }
    __syncthreads();
  }

#pragma unroll
  for (int nf = 0; nf < 8; ++nf) {
    const float bias = bout[col0 + nf * 16 + l15];
#pragma unroll
    for (int r = 0; r < 4; ++r) {
      const int row = tok0 + w * 16 + lg * 4 + r;
      out[((size_t)b * NTOK + row) * DIMX + col0 + nf * 16 + l15] = acc[nf][r] + bias;
    }
  }
}

// ---------------------------------------------------------------------------
// Cooperative tail: phase A (bdwout, 512 blocks) -> phase B (weff, 128) ->
// phase C (out, all 1024). grid = 1024 @ 4 blocks/CU (LDS 19KB, VGPR<=128).
// ---------------------------------------------------------------------------
__global__ __launch_bounds__(256, 4) void k_tail(
    const float* __restrict__ partial, const float* __restrict__ Wout,
    const float* __restrict__ Wq, const float* __restrict__ x,
    const float* __restrict__ bout, unsigned short* __restrict__ tmpT,
    unsigned short* __restrict__ weffT, float* __restrict__ out)
{
  __shared__ float drow[4][64];
  __shared__ unsigned short wsl[2 * 128 * 36];
  cg::grid_group grid = cg::this_grid();

  if (blockIdx.x < 512)
    body_bdwout(blockIdx.x, threadIdx.x, drow, partial, Wout, tmpT);
  __threadfence();
  grid.sync();

  if (blockIdx.x < 128)
    body_weff(blockIdx.x, threadIdx.x, Wq, tmpT, weffT);
  __threadfence();
  grid.sync();

  body_out(blockIdx.x, threadIdx.x, wsl, x, weffT, bout, out);
}

// Fallback standalone kernels (used if cooperative launch is unavailable)
__global__ __launch_bounds__(256) void k_bdwout2(
    const float* __restrict__ partial, const float* __restrict__ Wout,
    unsigned short* __restrict__ tmpT)
{
  __shared__ float drow[4][64];
  body_bdwout(blockIdx.x, threadIdx.x, drow, partial, Wout, tmpT);
}

__global__ __launch_bounds__(256) void k_weff_mfma(
    const float* __restrict__ Wq, const unsigned short* __restrict__ tmpT,
    unsigned short* __restrict__ weffT)
{
  body_weff(blockIdx.x, threadIdx.x, Wq, tmpT, weffT);
}

__global__ __launch_bounds__(256) void k_out_mfma(
    const float* __restrict__ x, const unsigned short* __restrict__ weffT,
    const float* __restrict__ bout, float* __restrict__ out)
{
  __shared__ unsigned short wsl[2 * 128 * 36];
  body_out(blockIdx.x, threadIdx.x, wsl, x, weffT, bout, out);
}

// ---------------------------------------------------------------------------
extern "C" void kernel_launch(void* const* d_in, const int* in_sizes, int n_in,
                              void* d_out, int out_size, void* d_ws, size_t ws_size,
                              hipStream_t stream) {
  const float* x    = (const float*)d_in[0];
  const float* z    = (const float*)d_in[1];
  const float* Wq   = (const float*)d_in[2];
  const float* Wkv  = (const float*)d_in[3];
  const float* Wout = (const float*)d_in[4];
  const float* bout = (const float*)d_in[5];
  float* out = (float*)d_out;

  unsigned short* tmpT  = (unsigned short*)d_ws;              // 1MB
  unsigned short* wkvT  = tmpT + (size_t)NB * DIMX * INNER;   // 0.5MB
  unsigned short* weffT = wkvT + (size_t)(2 * INNER) * DIMX;  // 0.5MB

  // d_out is 32MB, fully rewritten by the tail's phase C:
  //  - first 16MB: z in bf16 (consumed by k_dots)
  //  - next 16MB : dots split-partials (consumed in tail phase A)
  unsigned short* zbf = (unsigned short*)d_out;
  const float* partial = (const float*)((char*)d_out + ((size_t)16 << 20));
  float* partial_w = (float*)partial;

  k_pre<<<2112, 256, 0, stream>>>(z, zbf, Wkv, wkvT);
  k_dots_mfma<<<NB * (NH / 2) * SPLIT, 256, 0, stream>>>(zbf, wkvT, partial_w);

  void* args[] = {(void*)&partial, (void*)&Wout, (void*)&Wq, (void*)&x,
                  (void*)&bout, (void*)&tmpT, (void*)&weffT, (void*)&out};
  hipError_t e = hipLaunchCooperativeKernel((const void*)k_tail, dim3(1024),
                                            dim3(256), args, 0, stream);
  if (e != hipSuccess) {
    // fallback: separate launches (round-15 behavior)
    k_bdwout2<<<512, 256, 0, stream>>>(partial, Wout, tmpT);
    k_weff_mfma<<<128, 256, 0, stream>>>(Wq, tmpT, weffT);
    k_out_mfma<<<1024, 256, 0, stream>>>(x, weffT, bout, out);
  }
}

// Round 17
// 83.299 us; speedup vs baseline: 5.9583x; 5.9583x over previous
//
#include <hip/hip_runtime.h>
#include <cstddef>

#define NB    4
#define NTOK  8192
#define DIMX  256
#define NH    8
#define HD    64
#define INNER 512
#define SPLIT 32
#define EPS   1e-5f

typedef __attribute__((ext_vector_type(8))) short short8;
typedef __attribute__((ext_vector_type(4))) float f32x4;

__device__ __forceinline__ unsigned short f2bf(float f) {
  union { float f; unsigned u; } v; v.f = f;
  unsigned r = v.u + 0x7fffu + ((v.u >> 16) & 1u);   // RNE
  return (unsigned short)(r >> 16);
}

__device__ __forceinline__ short8 cvt8(float4 a, float4 b) {
  short8 p;
  p[0] = (short)f2bf(a.x); p[1] = (short)f2bf(a.y);
  p[2] = (short)f2bf(a.z); p[3] = (short)f2bf(a.w);
  p[4] = (short)f2bf(b.x); p[5] = (short)f2bf(b.y);
  p[6] = (short)f2bf(b.z); p[7] = (short)f2bf(b.w);
  return p;
}

// ---------------------------------------------------------------------------
// Fused pre-pass: blocks 0..2047 convert z fp32->bf16 (16 elems/thread);
// blocks 2048..2111 transpose Wkv [256][1024] fp32 -> wkvT [1024][256] bf16.
// ---------------------------------------------------------------------------
__global__ __launch_bounds__(256) void k_pre(
    const float* __restrict__ z, unsigned short* __restrict__ zb,
    const float* __restrict__ Wkv, unsigned short* __restrict__ wkvT)
{
  __shared__ unsigned short t[64][68];
  if (blockIdx.x < 2048) {
    const size_t i = ((size_t)blockIdx.x * 256 + threadIdx.x) * 16;
    float4 a0 = *(const float4*)(z + i);
    float4 a1 = *(const float4*)(z + i + 4);
    float4 a2 = *(const float4*)(z + i + 8);
    float4 a3 = *(const float4*)(z + i + 12);
    *(short8*)(zb + i) = cvt8(a0, a1);
    *(short8*)(zb + i + 8) = cvt8(a2, a3);
  } else {
    const int tid = threadIdx.x;
    const int bb = blockIdx.x - 2048;
    const int r0 = (bb & 3) * 64;
    const int c0 = (bb >> 2) * 64;
    const int r = tid >> 2;
    const int c4 = (tid & 3) * 16;
#pragma unroll
    for (int j = 0; j < 4; ++j) {
      float4 v = *(const float4*)(Wkv + (size_t)(r0 + r) * (2 * INNER) + c0 + c4 + j * 4);
      t[r][c4 + j * 4 + 0] = f2bf(v.x);
      t[r][c4 + j * 4 + 1] = f2bf(v.y);
      t[r][c4 + j * 4 + 2] = f2bf(v.z);
      t[r][c4 + j * 4 + 3] = f2bf(v.w);
    }
    __syncthreads();
    const int cc = tid >> 2;
    const int rr4 = (tid & 3) * 16;
    short8 o0, o1;
#pragma unroll
    for (int i = 0; i < 8; ++i) o0[i] = (short)t[rr4 + i][cc];
#pragma unroll
    for (int i = 0; i < 8; ++i) o1[i] = (short)t[rr4 + 8 + i][cc];
    unsigned short* dst = wkvT + (size_t)(c0 + cc) * DIMX + r0 + rr4;
    *(short8*)(dst) = o0;
    *(short8*)(dst + 8) = o1;
  }
}

// ---------------------------------------------------------------------------
// dots partials via MFMA, 2 heads per block. (round-14/15 proven)
// grid = NB * (NH/2) * SPLIT = 512 blocks, 256 threads.
// ---------------------------------------------------------------------------
__global__ __launch_bounds__(256, 2) void k_dots_mfma(
    const unsigned short* __restrict__ zb, const unsigned short* __restrict__ wkvT,
    float* __restrict__ partial)
{
  const int tid  = threadIdx.x;
  const int lane = tid & 63;
  const int w    = tid >> 6;       // wave 0..3
  const int hh   = w >> 1;         // head within pair
  const int side = w & 1;          // 0=k, 1=v
  const int l15  = lane & 15;
  const int lg   = lane >> 4;      // 0..3

  const int bid = blockIdx.x;
  const int s  = bid & (SPLIT - 1);
  const int hp = (bid >> 5) & 3;
  const int b  = bid >> 7;
  const int h  = hp * 2 + hh;

  __shared__ unsigned short zs[2][32][268];   // dbuf: 32 tok x 256 dims
  __shared__ unsigned short kv2[2][256][36];  // dbuf: [hh*128 + side*64 + dim][tok]

  // A-fragments: this wave's 64 dims (k or v of head h), all 8 K-steps.
  short8 awf[4][8];
#pragma unroll
  for (int mf = 0; mf < 4; ++mf) {
    const int dim = mf * 16 + l15;                       // 0..63
    const int gd = (side == 0) ? (h * HD + dim) : (INNER + h * HD + dim);
    const unsigned short* base = wkvT + (size_t)gd * DIMX + lg * 8;
#pragma unroll
    for (int kk = 0; kk < 8; ++kk)
      awf[mf][kk] = *(const short8*)(base + kk * 32);
  }

  f32x4 dacc[2][4];
#pragma unroll
  for (int mfr = 0; mfr < 2; ++mfr)
#pragma unroll
    for (int nfc = 0; nfc < 4; ++nfc) dacc[mfr][nfc] = (f32x4){0.f, 0.f, 0.f, 0.f};

  // staging: 32 rows, 8 threads/row, 32 bf16 (4 x short8) per thread
  const int zr = tid >> 3;
  const int zc = (tid & 7) * 32;
  const unsigned short* zbase = zb + ((size_t)b * NTOK + s * 256 + zr) * DIMX + zc;

  // prologue: stage tile 0 into buffer 0
  {
    short8 pre[4];
#pragma unroll
    for (int j = 0; j < 4; ++j) pre[j] = *(const short8*)(zbase + j * 8);
#pragma unroll
    for (int j = 0; j < 4; ++j) *(short8*)&zs[0][zr][zc + j * 8] = pre[j];
  }
  __syncthreads();

  int cur = 0;
  for (int tile = 0; tile < 8; ++tile) {
    // prefetch next z tile into regs
    short8 pre[4];
    if (tile < 7) {
      const unsigned short* src = zbase + (size_t)(tile + 1) * 32 * DIMX;
#pragma unroll
      for (int j = 0; j < 4; ++j) pre[j] = *(const short8*)(src + j * 8);
    }

    // ---- phase 1: this side's 64 dims x 32 tokens ----
    f32x4 acc[4][2];
#pragma unroll
    for (int mf = 0; mf < 4; ++mf)
#pragma unroll
      for (int nf = 0; nf < 2; ++nf) acc[mf][nf] = (f32x4){0.f, 0.f, 0.f, 0.f};

#pragma unroll
    for (int kk = 0; kk < 8; ++kk) {
      short8 bfr[2];
#pragma unroll
      for (int nf = 0; nf < 2; ++nf)
        bfr[nf] = *(const short8*)&zs[cur][nf * 16 + l15][kk * 32 + lg * 8];
#pragma unroll
      for (int mf = 0; mf < 4; ++mf)
#pragma unroll
        for (int nf = 0; nf < 2; ++nf)
          acc[mf][nf] = __builtin_amdgcn_mfma_f32_16x16x32_bf16(
              awf[mf][kk], bfr[nf], acc[mf][nf], 0, 0, 0);
    }

    // ---- per-token stats: wave-local (all 64 dims of this side in-wave) ----
    float mu[2], rs[2];
#pragma unroll
    for (int nf = 0; nf < 2; ++nf) {
      float a = 0.f, q = 0.f;
#pragma unroll
      for (int mf = 0; mf < 4; ++mf)
#pragma unroll
        for (int r = 0; r < 4; ++r) {
          float v = acc[mf][nf][r];
          a += v; q += v * v;
        }
      a += __shfl_xor(a, 16); a += __shfl_xor(a, 32);
      q += __shfl_xor(q, 16); q += __shfl_xor(q, 32);
      const float m = a * (1.f / 64.f);
      mu[nf] = m;
      rs[nf] = rsqrtf(q * (1.f / 64.f) - m * m + EPS);
    }

    // ---- normalize, write kv2[cur] ----
#pragma unroll
    for (int mf = 0; mf < 4; ++mf)
#pragma unroll
      for (int nf = 0; nf < 2; ++nf)
#pragma unroll
        for (int r = 0; r < 4; ++r)
          kv2[cur][hh * 128 + side * 64 + mf * 16 + lg * 4 + r][nf * 16 + l15] =
              f2bf((acc[mf][nf][r] - mu[nf]) * rs[nf]);

    // stage next z tile into zs[cur^1]
    if (tile < 7) {
#pragma unroll
      for (int j = 0; j < 4; ++j) *(short8*)&zs[cur ^ 1][zr][zc + j * 8] = pre[j];
    }
    __syncthreads();   // kv2[cur] + zs[cur^1] ready

    // ---- phase 3: dots(head h) rows [side*32,+32) x all 64 v-cols ----
    {
      const int kvb = hh * 128;
      short8 a2[2], b2[4];
#pragma unroll
      for (int mfr = 0; mfr < 2; ++mfr)
        a2[mfr] = *(const short8*)&kv2[cur][kvb + side * 32 + mfr * 16 + l15][lg * 8];
#pragma unroll
      for (int nfc = 0; nfc < 4; ++nfc)
        b2[nfc] = *(const short8*)&kv2[cur][kvb + 64 + nfc * 16 + l15][lg * 8];
#pragma unroll
      for (int mfr = 0; mfr < 2; ++mfr)
#pragma unroll
        for (int nfc = 0; nfc < 4; ++nfc)
          dacc[mfr][nfc] = __builtin_amdgcn_mfma_f32_16x16x32_bf16(
              a2[mfr], b2[nfc], dacc[mfr][nfc], 0, 0, 0);
    }
    cur ^= 1;
  }

  float* pb = partial + ((size_t)((b * NH + h) * SPLIT + s)) * 4096;
#pragma unroll
  for (int mfr = 0; mfr < 2; ++mfr)
#pragma unroll
    for (int nfc = 0; nfc < 4; ++nfc)
#pragma unroll
      for (int r = 0; r < 4; ++r)
        pb[(side * 32 + mfr * 16 + lg * 4 + r) * 64 + nfc * 16 + l15] =
            dacc[mfr][nfc][r];
}

// ---------------------------------------------------------------------------
// Fused split-reduce + tmp GEMM; emits tmpT[b][c][k] in bf16
// (K-contiguous for the MFMA weff). grid = NB*128 = 512 blocks.
// ---------------------------------------------------------------------------
__global__ __launch_bounds__(256) void k_bdwout2(
    const float* __restrict__ partial, const float* __restrict__ Wout,
    unsigned short* __restrict__ tmpT)
{
  const int bid = blockIdx.x;
  const int b = bid >> 7;
  const int r4 = (bid & 127) * 4;
  const int h = r4 >> 6;
  const int c = threadIdx.x;

  __shared__ float drow[4][64];
  {
    const int rr = c >> 6;          // 0..3
    const int j = c & 63;
    const float* p = partial + (size_t)(b * NH + h) * SPLIT * 4096
                   + ((r4 & 63) + rr) * 64 + j;
    float s = 0.f;
#pragma unroll
    for (int i = 0; i < SPLIT; ++i) s += p[(size_t)i * 4096];
    drow[rr][j] = s * (1.f / (float)NTOK);
  }
  __syncthreads();

  float a0 = 0.f, a1 = 0.f, a2 = 0.f, a3 = 0.f;
#pragma unroll 8
  for (int j = 0; j < 64; ++j) {
    const float wv = Wout[(size_t)(h * 64 + j) * DIMX + c];
    a0 += drow[0][j] * wv;
    a1 += drow[1][j] * wv;
    a2 += drow[2][j] * wv;
    a3 += drow[3][j] * wv;
  }
  unsigned short* tt = tmpT + ((size_t)b * DIMX + c) * INNER + r4;
  tt[0] = f2bf(a0); tt[1] = f2bf(a1); tt[2] = f2bf(a2); tt[3] = f2bf(a3);
}

// ---------------------------------------------------------------------------
// weffT[b][c][r] = sum_k Wq[r][k] * tmpT[b][c][k] via MFMA.
// grid = NB*32 = 128 blocks (bid: b = bid>>5, rt = (bid>>3)&3, ct = bid&7),
// block tile = 64 rows x 32 cols, K = 512 (16 k-steps).
// ---------------------------------------------------------------------------
__global__ __launch_bounds__(256) void k_weff_mfma(
    const float* __restrict__ Wq, const unsigned short* __restrict__ tmpT,
    unsigned short* __restrict__ weffT)
{
  const int tid  = threadIdx.x;
  const int lane = tid & 63;
  const int w    = tid >> 6;
  const int l15  = lane & 15;
  const int lg   = lane >> 4;

  const int bid = blockIdx.x;
  const int b  = bid >> 5;
  const int rt = (bid >> 3) & 3;
  const int ct = bid & 7;
  const int r0 = rt * 64;
  const int c0 = ct * 32;

  const float* wq = Wq + (size_t)(r0 + w * 16 + l15) * INNER + lg * 8;
  const unsigned short* tb = tmpT + (size_t)b * DIMX * INNER + lg * 8;

  f32x4 acc[2];
  acc[0] = (f32x4){0.f, 0.f, 0.f, 0.f};
  acc[1] = (f32x4){0.f, 0.f, 0.f, 0.f};

#pragma unroll
  for (int kk = 0; kk < 16; ++kk) {
    float4 qa = *(const float4*)(wq + kk * 32);
    float4 qb = *(const float4*)(wq + kk * 32 + 4);
    short8 a = cvt8(qa, qb);
#pragma unroll
    for (int nf = 0; nf < 2; ++nf) {
      short8 b2 = *(const short8*)(tb + (size_t)(c0 + nf * 16 + l15) * INNER + kk * 32);
      acc[nf] = __builtin_amdgcn_mfma_f32_16x16x32_bf16(a, b2, acc[nf], 0, 0, 0);
    }
  }

#pragma unroll
  for (int nf = 0; nf < 2; ++nf) {
    const int c = c0 + nf * 16 + l15;
    const int r = r0 + w * 16 + lg * 4;
    unsigned long long pack = 0;
#pragma unroll
    for (int rr = 0; rr < 4; ++rr)
      pack |= (unsigned long long)f2bf(acc[nf][rr]) << (16 * rr);
    *(unsigned long long*)(weffT + ((size_t)b * DIMX + c) * DIMX + r) = pack;
  }
}

// ---------------------------------------------------------------------------
// out[b] = x[b] @ W_eff[b] + bout via MFMA, double-buffered LDS W slices.
// grid = NB*256 = 1024 blocks (bid = b*256 + ct*128 + mt), 256 thr.
// Block: 64 tokens x 128 cols. (round-12/14/15 proven)
// ---------------------------------------------------------------------------
__global__ __launch_bounds__(256) void k_out_mfma(
    const float* __restrict__ x, const unsigned short* __restrict__ weffT,
    const float* __restrict__ bout, float* __restrict__ out)
{
  const int tid  = threadIdx.x;
  const int lane = tid & 63;
  const int w    = tid >> 6;
  const int l15  = lane & 15;
  const int lg   = lane >> 4;

  const int bid = blockIdx.x;
  const int mt = bid & 127;
  const int ct = (bid >> 7) & 1;
  const int b  = bid >> 8;
  const int tok0 = mt * 64;
  const int col0 = ct * 128;

  __shared__ unsigned short wsl[2][128 * 36];   // k-slice: 128 cols x 32 k, pad 36

  // A-fragments: x row (tok0 + w*16 + l15), converted fp32->bf16.
  short8 afr[8];
  {
    const float* xr = x + ((size_t)b * NTOK + tok0 + w * 16 + l15) * DIMX + lg * 8;
#pragma unroll
    for (int kk = 0; kk < 8; ++kk) {
      float4 xa = *(const float4*)(xr + kk * 32);
      float4 xb = *(const float4*)(xr + kk * 32 + 4);
      afr[kk] = cvt8(xa, xb);
    }
  }

  f32x4 acc[8];
#pragma unroll
  for (int nf = 0; nf < 8; ++nf) acc[nf] = (f32x4){0.f, 0.f, 0.f, 0.f};

  // staging: thread t stages col (col0 + t>>1), k-half (t&1)*16 of each slice
  const unsigned short* wb = weffT + (size_t)b * DIMX * DIMX
                           + (size_t)(col0 + (tid >> 1)) * DIMX + (tid & 1) * 16;
  const int c36 = (tid >> 1) * 36 + (tid & 1) * 16;

  // prologue: stage slice 0
  *(short8*)&wsl[0][c36]     = *(const short8*)(wb);
  *(short8*)&wsl[0][c36 + 8] = *(const short8*)(wb + 8);
  __syncthreads();

  for (int kk = 0; kk < 8; ++kk) {
    short8 g0, g1;
    if (kk < 7) {
      g0 = *(const short8*)(wb + (kk + 1) * 32);
      g1 = *(const short8*)(wb + (kk + 1) * 32 + 8);
    }
#pragma unroll
    for (int nf = 0; nf < 8; ++nf) {
      short8 b2 = *(const short8*)&wsl[kk & 1][(nf * 16 + l15) * 36 + lg * 8];
      acc[nf] = __builtin_amdgcn_mfma_f32_16x16x32_bf16(afr[kk], b2, acc[nf], 0, 0, 0);
    }
    if (kk < 7) {
      *(short8*)&wsl[(kk + 1) & 1][c36]     = g0;
      *(short8*)&wsl[(kk + 1) & 1][c36 + 8] = g1;
    }
    __syncthreads();
  }

#pragma unroll
  for (int nf = 0; nf < 8; ++nf) {
    const float bias = bout[col0 + nf * 16 + l15];
#pragma unroll
    for (int r = 0; r < 4; ++r) {
      const int row = tok0 + w * 16 + lg * 4 + r;
      out[((size_t)b * NTOK + row) * DIMX + col0 + nf * 16 + l15] = acc[nf][r] + bias;
    }
  }
}

// ---------------------------------------------------------------------------
extern "C" void kernel_launch(void* const* d_in, const int* in_sizes, int n_in,
                              void* d_out, int out_size, void* d_ws, size_t ws_size,
                              hipStream_t stream) {
  const float* x    = (const float*)d_in[0];
  const float* z    = (const float*)d_in[1];
  const float* Wq   = (const float*)d_in[2];
  const float* Wkv  = (const float*)d_in[3];
  const float* Wout = (const float*)d_in[4];
  const float* bout = (const float*)d_in[5];
  float* out = (float*)d_out;

  unsigned short* tmpT  = (unsigned short*)d_ws;              // 4*256*512 bf16 = 1MB
  unsigned short* wkvT  = tmpT + (size_t)NB * DIMX * INNER;   // 0.5MB
  unsigned short* weffT = wkvT + (size_t)(2 * INNER) * DIMX;  // 0.5MB
  // ws total ~2MB

  // d_out is 32MB and fully rewritten by k_out_mfma at the end:
  //  - first 16MB: z in bf16
  //  - next 16MB : dots split-partials (1024 x 4096 f32)
  unsigned short* zbf = (unsigned short*)d_out;
  float* partial = (float*)((char*)d_out + ((size_t)16 << 20));

  k_pre<<<2112, 256, 0, stream>>>(z, zbf, Wkv, wkvT);
  k_dots_mfma<<<NB * (NH / 2) * SPLIT, 256, 0, stream>>>(zbf, wkvT, partial);
  k_bdwout2<<<NB * 128, 256, 0, stream>>>(partial, Wout, tmpT);
  k_weff_mfma<<<NB * 32, 256, 0, stream>>>(Wq, tmpT, weffT);
  k_out_mfma<<<NB * 256, 256, 0, stream>>>(x, weffT, bout, out);
}